// Round 4
// baseline (292.456 us; speedup 1.0000x reference)
//
#include <hip/hip_runtime.h>
#include <math.h>
#include <stdint.h>

#define NH 32
#define NKV 8
#define HD 128
#define HDIM 4096
#define KVDIM 1024
#define TPREV 16383
#define NCHUNK 256
#define CHUNK 64  // tokens per block, single pass

// ws layout (floats)
#define OFF_Q 0
#define OFF_K 4096
#define OFF_V 5120
#define OFF_PART 6144
#define PART_STRIDE 132  // 528B, 16B-aligned for float4 partial writes
#define OFF_CTX (OFF_PART + NH * NCHUNK * PART_STRIDE)  // 1087488 (~4.35MB)

__device__ __forceinline__ float wave_reduce_sum(float v) {
#pragma unroll
  for (int m = 32; m >= 1; m >>= 1) v += __shfl_xor(v, m, 64);
  return v;
}
__device__ __forceinline__ float wave_reduce_max(float v) {
#pragma unroll
  for (int m = 32; m >= 1; m >>= 1) v = fmaxf(v, __shfl_xor(v, m, 64));
  return v;
}
__device__ __forceinline__ float dot4(float4 a, float4 b) {
  return a.x * b.x + a.y * b.y + a.z * b.z + a.w * b.w;
}

// async global->LDS; LDS dst is WAVE-UNIFORM base + lane*16 (linear)
typedef const __attribute__((address_space(1))) unsigned int* gld_gp;
typedef __attribute__((address_space(3))) unsigned int* gld_lp;
__device__ __forceinline__ void cp16(const float* g, float* l) {
  __builtin_amdgcn_global_load_lds((gld_gp)(uintptr_t)g,
                                   (gld_lp)(uint32_t)(uintptr_t)l, 16, 0, 0);
}

// ---------------------------------------------------------------------------
// Kernel 1: fused QKV matvec + RoPE (unchanged).
// ---------------------------------------------------------------------------
__global__ __launch_bounds__(256) void qkv_rope_kernel(
    const float* __restrict__ Wq, const float* __restrict__ Wk,
    const float* __restrict__ Wv, const float* __restrict__ hidden,
    const int* __restrict__ pos_p, float* __restrict__ ws) {
  int r = blockIdx.x * 4 + (threadIdx.x >> 6);
  int lane = threadIdx.x & 63;
  const float* W;
  int wr;
  if (r < HDIM) {
    W = Wq; wr = r;
  } else if (r < HDIM + KVDIM) {
    W = Wk; wr = r - HDIM;
  } else {
    W = Wv; wr = r - HDIM - KVDIM;
  }
  const float4* w4 = (const float4*)(W + (size_t)wr * HDIM);
  const float4* h4 = (const float4*)hidden;
  float s = 0.f;
#pragma unroll
  for (int base = 0; base < 16; base += 8) {
    float4 a[8], b[8];
#pragma unroll
    for (int j = 0; j < 8; ++j) a[j] = w4[lane + 64 * (base + j)];
#pragma unroll
    for (int j = 0; j < 8; ++j) b[j] = h4[lane + 64 * (base + j)];
#pragma unroll
    for (int j = 0; j < 8; ++j) s += dot4(a[j], b[j]);
  }
  s = wave_reduce_sum(s);
  __shared__ float rs[4];
  if (lane == 0) rs[threadIdx.x >> 6] = s;
  __syncthreads();
  if (threadIdx.x < 2) {
    int r0 = blockIdx.x * 4 + (int)threadIdx.x * 2;
    float S0 = rs[threadIdx.x * 2], S1 = rs[threadIdx.x * 2 + 1];
    if (r0 < HDIM + KVDIM) {
      int j = (r0 & (HD - 1)) >> 1;  // 0..63
      double lowp = 1.0;
      if (j & 1) lowp *= 0.8659643233600653;   // 10^(-1/16)
      if (j & 2) lowp *= 0.7498942093324559;   // 10^(-1/8)
      if (j & 4) lowp *= 0.5623413251903491;   // 10^(-1/4)
      if (j & 8) lowp *= 0.31622776601683794;  // 10^(-1/2)
      double hi = (j & 16) ? 0.1 : 1.0;
      if (j & 32) hi *= 0.01;
      double f = (double)(*pos_p) * (lowp * hi);
      double k2 = floor(f * 0.15915494309189535);
      double rr = f - k2 * 6.283185307179586;
      float fr = (float)rr;
      float c = cosf(fr), sn = sinf(fr);
      ws[r0] = S0 * c - S1 * sn;
      ws[r0 + 1] = S0 * sn + S1 * c;
    } else {
      ws[r0] = S0;
      ws[r0 + 1] = S1;
    }
  }
}

// ---------------------------------------------------------------------------
// Kernel 2: flash-decoding, SINGLE-PASS 64-token chunks. Grid 2048 = 4
// resident blocks/CU (LDS 36KB, VGPR<=128 via launch_bounds(256,4)).
// Rationale: r0 (reg-stream, 2/CU) and r3 (async dbuf, 2/CU) both hit
// ~57us with all pipes <20% -> latency-serial chain amortized over too few
// independent streams. This version: 4 barriers/block, NO serial tid<4
// stage, no online-softmax state; cross-block TLP does the overlap.
// K via gl_lds (swizzled source, conflict-free ds_read_b128); V straight
// to registers, 4-deep batches. vacc aliases Klds after QK.
// ---------------------------------------------------------------------------
__global__ __launch_bounds__(256, 4) void attn_chunk_kernel(
    const float* __restrict__ k_cache, const float* __restrict__ v_cache,
    float* __restrict__ ws) {
  int g = blockIdx.x >> 8;  // NCHUNK = 256
  int c = blockIdx.x & 255;
  int t0 = c * CHUNK;
  int tid = threadIdx.x;
  int l = tid & 63, w = tid >> 6;

  __shared__ __align__(16) float Klds[CHUNK * HD];  // 32KB; vacc alias later
  __shared__ __align__(16) float qs[4 * HD];        // 2KB linear
  __shared__ float sc[CHUNK * 5];                   // 1.25KB
  __shared__ float wredm[4][4], wredl[4][4];

  // ---- stage q (waves 0,1; 1KB each) + K (8 cp16/wave, swizzled src) ----
  if (w < 2)
    cp16(ws + OFF_Q + (g << 9) + (w << 8) + (l << 2), qs + (w << 8));
#pragma unroll
  for (int i = 0; i < 8; ++i) {
    int tokA = (w << 4) + 2 * i;
    int toks = tokA + (l >> 5);
    int gt = t0 + toks;
    if (gt >= TPREV) gt = 0;
    cp16(k_cache + (size_t)gt * KVDIM + g * HD + (((l & 31) ^ (toks & 7)) << 2),
         Klds + (tokA << 7));
  }
  __syncthreads();  // drains vmcnt(0): q + K visible

  const float rscale = 0.08838834764831845f;  // 1/sqrt(128)
  // --- QK: 16 distinct tokens per 16-lane phase; qq = 32-dim quarter ---
  int tokl = (w << 4) + (l & 15);
  int qq = l >> 4;
  int t7 = tokl & 7;
  const float4* K4 = (const float4*)Klds;
  const float4* q4 = (const float4*)qs;
  float s0 = 0.f, s1 = 0.f, s2 = 0.f, s3 = 0.f;
#pragma unroll
  for (int j = 0; j < 8; ++j) {
    float4 kk = K4[(tokl << 5) + (qq << 3) + (j ^ t7)];
    float4 qa = q4[0 * 32 + (qq << 3) + j];
    float4 qb = q4[1 * 32 + (qq << 3) + j];
    float4 qc = q4[2 * 32 + (qq << 3) + j];
    float4 qd_ = q4[3 * 32 + (qq << 3) + j];
    s0 += dot4(kk, qa); s1 += dot4(kk, qb);
    s2 += dot4(kk, qc); s3 += dot4(kk, qd_);
  }
  s0 += __shfl_xor(s0, 16, 64); s0 += __shfl_xor(s0, 32, 64);
  s1 += __shfl_xor(s1, 16, 64); s1 += __shfl_xor(s1, 32, 64);
  s2 += __shfl_xor(s2, 16, 64); s2 += __shfl_xor(s2, 32, 64);
  s3 += __shfl_xor(s3, 16, 64); s3 += __shfl_xor(s3, 32, 64);
  s0 *= rscale; s1 *= rscale; s2 *= rscale; s3 *= rscale;
  if (t0 + tokl >= TPREV) {
    s0 = -1e30f; s1 = -1e30f; s2 = -1e30f; s3 = -1e30f;
  }

  // --- block max per head: wave reduce + LDS, read by ALL threads ---
  float m0 = wave_reduce_max(s0), m1 = wave_reduce_max(s1);
  float m2 = wave_reduce_max(s2), m3 = wave_reduce_max(s3);
  if (l == 0) {
    wredm[w][0] = m0; wredm[w][1] = m1; wredm[w][2] = m2; wredm[w][3] = m3;
  }
  __syncthreads();
  float mh0 = fmaxf(fmaxf(wredm[0][0], wredm[1][0]),
                    fmaxf(wredm[2][0], wredm[3][0]));
  float mh1 = fmaxf(fmaxf(wredm[0][1], wredm[1][1]),
                    fmaxf(wredm[2][1], wredm[3][1]));
  float mh2 = fmaxf(fmaxf(wredm[0][2], wredm[1][2]),
                    fmaxf(wredm[2][2], wredm[3][2]));
  float mh3 = fmaxf(fmaxf(wredm[0][3], wredm[1][3]),
                    fmaxf(wredm[2][3], wredm[3][3]));

  // --- exp + sum (each token counted 4x in wave sum -> *0.25) ---
  float e0 = expf(s0 - mh0), e1 = expf(s1 - mh1);
  float e2 = expf(s2 - mh2), e3 = expf(s3 - mh3);
  if (qq == 0) {
    sc[tokl * 5 + 0] = e0; sc[tokl * 5 + 1] = e1;
    sc[tokl * 5 + 2] = e2; sc[tokl * 5 + 3] = e3;
  }
  float l0 = 0.25f * wave_reduce_sum(e0), l1 = 0.25f * wave_reduce_sum(e1);
  float l2 = 0.25f * wave_reduce_sum(e2), l3 = 0.25f * wave_reduce_sum(e3);
  if (l == 0) {
    wredl[w][0] = l0; wredl[w][1] = l1; wredl[w][2] = l2; wredl[w][3] = l3;
  }
  __syncthreads();  // sc + wredl visible; all K reads done

  // --- PV: 8 tokens per 32-lane group, V straight from global, 4-deep ---
  int grp = tid >> 5, d4 = tid & 31;
  float4 acc0 = {0, 0, 0, 0}, acc1 = {0, 0, 0, 0};
  float4 acc2 = {0, 0, 0, 0}, acc3 = {0, 0, 0, 0};
  const float4 z4 = {0, 0, 0, 0};
#pragma unroll
  for (int base = 0; base < 8; base += 4) {
    float4 vv[4];
#pragma unroll
    for (int j = 0; j < 4; ++j) {
      int it = grp + 8 * (base + j);
      int t = t0 + it;
      vv[j] = (t < TPREV)
                  ? ((const float4*)(v_cache + (size_t)t * KVDIM + g * HD))[d4]
                  : z4;
    }
#pragma unroll
    for (int j = 0; j < 4; ++j) {
      int it = grp + 8 * (base + j);
      float p0 = sc[it * 5 + 0], p1 = sc[it * 5 + 1];
      float p2 = sc[it * 5 + 2], p3 = sc[it * 5 + 3];
      acc0.x = fmaf(p0, vv[j].x, acc0.x); acc0.y = fmaf(p0, vv[j].y, acc0.y);
      acc0.z = fmaf(p0, vv[j].z, acc0.z); acc0.w = fmaf(p0, vv[j].w, acc0.w);
      acc1.x = fmaf(p1, vv[j].x, acc1.x); acc1.y = fmaf(p1, vv[j].y, acc1.y);
      acc1.z = fmaf(p1, vv[j].z, acc1.z); acc1.w = fmaf(p1, vv[j].w, acc1.w);
      acc2.x = fmaf(p2, vv[j].x, acc2.x); acc2.y = fmaf(p2, vv[j].y, acc2.y);
      acc2.z = fmaf(p2, vv[j].z, acc2.z); acc2.w = fmaf(p2, vv[j].w, acc2.w);
      acc3.x = fmaf(p3, vv[j].x, acc3.x); acc3.y = fmaf(p3, vv[j].y, acc3.y);
      acc3.z = fmaf(p3, vv[j].z, acc3.z); acc3.w = fmaf(p3, vv[j].w, acc3.w);
    }
  }
  // vacc aliases Klds (K reads finished before previous barrier)
  float4* vacc4 = (float4*)Klds;
  vacc4[(grp * 4 + 0) * 32 + d4] = acc0;
  vacc4[(grp * 4 + 1) * 32 + d4] = acc1;
  vacc4[(grp * 4 + 2) * 32 + d4] = acc2;
  vacc4[(grp * 4 + 3) * 32 + d4] = acc3;
  __syncthreads();

  // --- cross-group reduce + partial write ---
  if (tid < 128) {
    int h = tid >> 5, dd = tid & 31;
    float4 s = {0, 0, 0, 0};
#pragma unroll
    for (int g2 = 0; g2 < 8; ++g2) {
      float4 v = vacc4[(g2 * 4 + h) * 32 + dd];
      s.x += v.x; s.y += v.y; s.z += v.z; s.w += v.w;
    }
    float* dst = ws + OFF_PART +
                 ((size_t)(g * 4 + h) * NCHUNK + c) * PART_STRIDE + (dd << 2);
    *(float4*)dst = s;
  }
  if (tid < 4) {
    float mh = fmaxf(fmaxf(wredm[0][tid], wredm[1][tid]),
                     fmaxf(wredm[2][tid], wredm[3][tid]));
    float lh = wredl[0][tid] + wredl[1][tid] + wredl[2][tid] + wredl[3][tid];
    float* base =
        ws + OFF_PART + ((size_t)(g * 4 + tid) * NCHUNK + c) * PART_STRIDE;
    base[128] = mh;
    base[129] = lh;
  }
}

// ---------------------------------------------------------------------------
// Kernel 3: combine 256 partials + new token per q head. 256 threads.
// ---------------------------------------------------------------------------
__global__ __launch_bounds__(256) void combine_kernel(float* __restrict__ ws) {
  int h = blockIdx.x;
  int g = h >> 2;
  int tid = threadIdx.x;
  const float rscale = 0.08838834764831845f;
  const float* ph = ws + OFF_PART + (size_t)h * NCHUNK * PART_STRIDE;

  __shared__ float red[HD];
  __shared__ float wexp[NCHUNK];
  __shared__ float wm[4], wl[4];
  __shared__ float acc2[HD];

  // dot(q_h, k_new)
  if (tid < HD) red[tid] = ws[OFF_Q + h * HD + tid] * ws[OFF_K + g * HD + tid];
  __syncthreads();
#pragma unroll
  for (int s2 = 64; s2 >= 1; s2 >>= 1) {
    if (tid < s2 && tid + s2 < HD) red[tid] += red[tid + s2];
    __syncthreads();
  }
  float snew = red[0] * rscale;

  // all 256 chunk (m,l) pairs: one per thread, block-reduce across 4 waves
  float mv = ph[(size_t)tid * PART_STRIDE + 128];
  float lv = ph[(size_t)tid * PART_STRIDE + 129];
  float mw = wave_reduce_max(mv);
  if ((tid & 63) == 0) wm[tid >> 6] = mw;
  __syncthreads();
  float M = fmaxf(fmaxf(fmaxf(wm[0], wm[1]), fmaxf(wm[2], wm[3])), snew);
  float w = expf(mv - M);
  wexp[tid] = w;
  float lw = wave_reduce_sum(lv * w);
  if ((tid & 63) == 0) wl[tid >> 6] = lw;
  __syncthreads();
  float en = expf(snew - M);
  float L = wl[0] + wl[1] + wl[2] + wl[3] + en;

  // accumulate: 2 chunk-halves x 128 dims, 128 iters each
  int half = tid >> 7, d = tid & 127;
  float acc = 0.f;
  int cbeg = half * (NCHUNK / 2);
#pragma unroll 8
  for (int c2 = cbeg; c2 < cbeg + NCHUNK / 2; ++c2)
    acc = fmaf(ph[(size_t)c2 * PART_STRIDE + d], wexp[c2], acc);
  if (half == 0) acc2[d] = acc;
  __syncthreads();
  if (half == 1) acc2[d] += acc;
  __syncthreads();
  if (tid < HD)
    ws[OFF_CTX + h * HD + tid] =
        (acc2[tid] + en * ws[OFF_V + g * HD + tid]) / L;
}

// ---------------------------------------------------------------------------
// Kernel 4: out = Wo @ ctx. One row per wave, batched loads, no barriers.
// ---------------------------------------------------------------------------
__global__ __launch_bounds__(256) void out_matvec_kernel(
    const float* __restrict__ Wo, const float* __restrict__ ws,
    float* __restrict__ out) {
  int r = blockIdx.x * 4 + (threadIdx.x >> 6);
  int lane = threadIdx.x & 63;
  const float4* w4 = (const float4*)(Wo + (size_t)r * HDIM);
  const float4* x4 = (const float4*)(ws + OFF_CTX);
  float s = 0.f;
#pragma unroll
  for (int base = 0; base < 16; base += 8) {
    float4 a[8], b[8];
#pragma unroll
    for (int j = 0; j < 8; ++j) a[j] = w4[lane + 64 * (base + j)];
#pragma unroll
    for (int j = 0; j < 8; ++j) b[j] = x4[lane + 64 * (base + j)];
#pragma unroll
    for (int j = 0; j < 8; ++j) s += dot4(a[j], b[j]);
  }
  s = wave_reduce_sum(s);
  if (lane == 0) out[r] = s;
}

extern "C" void kernel_launch(void* const* d_in, const int* in_sizes, int n_in,
                              void* d_out, int out_size, void* d_ws,
                              size_t ws_size, hipStream_t stream) {
  const float* hidden = (const float*)d_in[0];
  const float* k_cache = (const float*)d_in[1];
  const float* v_cache = (const float*)d_in[2];
  const float* Wq = (const float*)d_in[3];
  const float* Wk = (const float*)d_in[4];
  const float* Wv = (const float*)d_in[5];
  const float* Wo = (const float*)d_in[6];
  const int* pos = (const int*)d_in[7];
  float* out = (float*)d_out;
  float* ws = (float*)d_ws;

  qkv_rope_kernel<<<(HDIM + 2 * KVDIM) / 4, 256, 0, stream>>>(Wq, Wk, Wv,
                                                              hidden, pos, ws);
  attn_chunk_kernel<<<NKV * NCHUNK, 256, 0, stream>>>(k_cache, v_cache, ws);
  combine_kernel<<<NH, 256, 0, stream>>>(ws);
  out_matvec_kernel<<<HDIM / 4, 256, 0, stream>>>(Wo, ws, out);
}